// Round 2
// baseline (396.902 us; speedup 1.0000x reference)
//
#include <hip/hip_runtime.h>
#include <hip/hip_bf16.h>

typedef unsigned short u16;
typedef __bf16 bf16x8 __attribute__((ext_vector_type(8)));
typedef float f32x4 __attribute__((ext_vector_type(4)));
typedef u16 u16x8 __attribute__((ext_vector_type(8)));

__device__ __forceinline__ u16 f2bf(float f) {
    __bf16 h = (__bf16)f;                 // RNE
    return __builtin_bit_cast(unsigned short, h);
}

__device__ __forceinline__ void gl_lds16(const u16* g, u16* l) {
    __builtin_amdgcn_global_load_lds(
        (const __attribute__((address_space(1))) void*)g,
        (__attribute__((address_space(3))) void*)l, 16, 0, 0);
}

// ---------------------------------------------------------------------------
// Kernel 1: ternary quantization (unchanged — correct, ~few µs).
// wq[o][f][ci] bf16, K-order = f*256 + ci. alpha[o] fp32.
// ---------------------------------------------------------------------------
__global__ __launch_bounds__(256) void quant_kernel(
        const float* __restrict__ w, u16* __restrict__ wq,
        float* __restrict__ alpha) {
    int o = blockIdx.x;
    int t = threadIdx.x;          // t == ci
    const float* wo = w + (size_t)o * 2304;
    float v[9];
    double asum = 0.0;
    #pragma unroll
    for (int i = 0; i < 9; ++i) { v[i] = wo[t * 9 + i]; asum += fabs((double)v[i]); }
    #pragma unroll
    for (int off = 32; off > 0; off >>= 1) asum += __shfl_down(asum, off, 64);
    __shared__ double red[4];
    int wv = t >> 6, lane = t & 63;
    if (lane == 0) red[wv] = asum;
    __syncthreads();
    double delta = 0.7 * ((red[0] + red[1] + red[2] + red[3]) / 2304.0);

    double msum = 0.0; int cnt = 0;
    #pragma unroll
    for (int i = 0; i < 9; ++i) {
        double f = (double)v[i];
        float tv = 0.f;
        if (f > delta) tv = 1.f;
        else if (f < -delta) tv = -1.f;
        if (tv != 0.f) { msum += fabs(f); cnt++; }
        wq[(size_t)o * 2304 + i * 256 + t] = f2bf(tv);
    }
    #pragma unroll
    for (int off = 32; off > 0; off >>= 1) {
        msum += __shfl_down(msum, off, 64);
        cnt  += __shfl_down(cnt,  off, 64);
    }
    __shared__ double red2[4];
    __shared__ int    redc[4];
    if (lane == 0) { red2[wv] = msum; redc[wv] = cnt; }
    __syncthreads();
    if (t == 0) {
        double ms = red2[0] + red2[1] + red2[2] + red2[3];
        int c = redc[0] + redc[1] + redc[2] + redc[3];
        alpha[o] = (float)(ms / (double)(c > 0 ? c : 1));
    }
}

// ---------------------------------------------------------------------------
// Kernel 2: x NCHW fp32 -> padded Xp[img][cihi32][hp58][wp58][cilo8] bf16.
// Borders pre-zeroed by hipMemsetAsync; this writes interior only.
// grid (img=32, cihi=32, hg=4): block = 8 c x 14 h x 56 w slab.
// Read: float4 fully contiguous per (c)-slab. LDS [h14][cilo8][w56].
// Write: u16x8 (8 channels) x 56 lanes = 896 B contiguous per h-row.
// ---------------------------------------------------------------------------
__global__ __launch_bounds__(256) void pad_kernel(
        const float* __restrict__ x, u16* __restrict__ xp) {
    int img  = blockIdx.x;
    int cihi = blockIdx.y;
    int hg   = blockIdx.z;
    int t = threadIdx.x;
    __shared__ u16 tile[14 * 8 * 56];   // [h][cilo][w]

    // read phase: 1568 float4 tasks; g = cilo*196 + (h*14 + s)
    const float* xb = x + ((size_t)img * 256 + cihi * 8) * 3136 + hg * 784;
    #pragma unroll
    for (int k = 0; k < 7; ++k) {
        int g = k * 256 + t;
        if (g < 1568) {
            int cilo = g / 196;
            int r = g - cilo * 196;          // r = h*14 + s
            f32x4 v = *(const f32x4*)(xb + (size_t)cilo * 3136 + r * 4);
            int h = r / 14, s = r - h * 14;
            u16* dst = &tile[(h * 8 + cilo) * 56 + s * 4];
            dst[0] = f2bf(v[0]); dst[1] = f2bf(v[1]);
            dst[2] = f2bf(v[2]); dst[3] = f2bf(v[3]);
        }
    }
    __syncthreads();
    // write phase: 784 u16x8 tasks; g = h*56 + w
    u16* ob = xp + (((size_t)(img * 32 + cihi) * 58 + (hg * 14 + 1)) * 58 + 1) * 8;
    #pragma unroll
    for (int k = 0; k < 4; ++k) {
        int g = k * 256 + t;
        if (g < 784) {
            int h = g / 56, w = g - h * 56;
            u16x8 v;
            #pragma unroll
            for (int j = 0; j < 8; ++j) v[j] = tile[(h * 8 + j) * 56 + w];
            *(u16x8*)(ob + ((size_t)h * 58 + w) * 8) = v;
        }
    }
}

// ---------------------------------------------------------------------------
// Kernel 3: implicit GEMM, m97-style. LDS [sub4][row128][cilo8] per operand,
// double-buffered; staging via global_load_lds width=16 (wave = sub, lane =
// row -> B loads are 1 KB contiguous per wave). Prefetch chunk kc+1 after the
// barrier so it overlaps the 64 MFMAs of chunk kc.
// ---------------------------------------------------------------------------
__global__ __launch_bounds__(256) void conv_gemm(
        const u16* __restrict__ Wq, const u16* __restrict__ Xp,
        const float* __restrict__ alpha, float* __restrict__ out) {
    __shared__ u16 lsA[2][4096];   // [buf][sub*1024 + row*8], 8 KB each
    __shared__ u16 lsB[2][4096];

    // XCD-aware swizzle: xcd = bid&7 owns contiguous nt range (B L2 reuse)
    int bid = blockIdx.x;
    int xcd = bid & 7, idx = bid >> 3;           // idx 0..195
    int mt = idx & 1;
    unsigned nt = (unsigned)(xcd * 98 + (idx >> 1));   // 0..783
    int o_base = mt * 128;
    unsigned sp_base = nt * 128u;

    int t = threadIdx.x;
    int lane = t & 63, wave = t >> 6;
    int wm = (wave >> 1) * 64, wn = (wave & 1) * 64;

    // staging bases: lane = row
    const u16* aBase0 = Wq + (size_t)(o_base + lane) * 2304;
    const u16* aBase1 = aBase0 + (size_t)64 * 2304;

    unsigned sp0 = sp_base + (unsigned)lane;
    unsigned sp1 = sp0 + 64u;
    unsigned img0 = sp0 / 3136u, rem0 = sp0 - img0 * 3136u;
    unsigned oh0 = rem0 / 56u,   ow0 = rem0 - oh0 * 56u;
    unsigned img1 = sp1 / 3136u, rem1 = sp1 - img1 * 3136u;
    unsigned oh1 = rem1 / 56u,   ow1 = rem1 - oh1 * 56u;
    // base at cihi=0, kh=0, kw=0
    const u16* bBase0 = Xp + ((size_t)(img0 * 32) * 58 + oh0) * 58 * 8 + ow0 * 8;
    const u16* bBase1 = Xp + ((size_t)(img1 * 32) * 58 + oh1) * 58 * 8 + ow1 * 8;

    u16* dA = &lsA[0][wave * 1024];
    u16* dB = &lsB[0][wave * 1024];

    // stage chunk kc into buffer b
    auto stage = [&](int kc, int b) {
        int f  = kc >> 3;
        int kh = f / 3, kw = f - kh * 3;
        unsigned cihi = (unsigned)((kc & 7) * 4 + wave);
        unsigned bOff = cihi * 26912u + (unsigned)kh * 464u + (unsigned)kw * 8u;
        unsigned aOff = (unsigned)(kc * 32 + wave * 8);
        u16* da = dA + b * 4096;   // wrong-dim trick avoided: see note below
        u16* db = dB + b * 4096;
        gl_lds16(aBase0 + aOff, da);
        gl_lds16(aBase1 + aOff, da + 512);
        gl_lds16(bBase0 + bOff, db);
        gl_lds16(bBase1 + bOff, db + 512);
    };
    // note: &lsA[1][x] == &lsA[0][x] + 4096 — the +b*4096 indexing is exact.

    f32x4 acc[4][4] = {};
    int row16 = lane & 15, quad = lane >> 4;

    stage(0, 0);
    int p = 0;
    for (int kc = 0; kc < 72; ++kc) {
        __syncthreads();              // drains vmcnt -> buf[p] ready; readers of buf[1-p] done
        if (kc + 1 < 72) stage(kc + 1, p ^ 1);

        const u16* A = &lsA[p][0];
        const u16* B = &lsB[p][0];
        bf16x8 af[4], bfr[4];
        #pragma unroll
        for (int i = 0; i < 4; ++i)
            af[i] = *(const bf16x8*)&A[(quad * 128 + wm + i * 16 + row16) * 8];
        #pragma unroll
        for (int j = 0; j < 4; ++j)
            bfr[j] = *(const bf16x8*)&B[(quad * 128 + wn + j * 16 + row16) * 8];
        #pragma unroll
        for (int i = 0; i < 4; ++i)
            #pragma unroll
            for (int j = 0; j < 4; ++j)
                acc[i][j] = __builtin_amdgcn_mfma_f32_16x16x32_bf16(
                                af[i], bfr[j], acc[i][j], 0, 0, 0);
        p ^= 1;
    }

    // epilogue: C/D layout col=lane&15 (sp), row=quad*4+reg (o)
    int col = lane & 15;
    float al[4][4];
    #pragma unroll
    for (int i = 0; i < 4; ++i)
        #pragma unroll
        for (int rg = 0; rg < 4; ++rg)
            al[i][rg] = alpha[o_base + wm + i * 16 + quad * 4 + rg];

    #pragma unroll
    for (int j = 0; j < 4; ++j) {
        unsigned sp = sp_base + (unsigned)(wn + j * 16 + col);
        unsigned img = sp / 3136u;
        unsigned spi = sp - img * 3136u;
        float* ob = out + (size_t)img * 256 * 3136 + spi;
        #pragma unroll
        for (int i = 0; i < 4; ++i) {
            int o = o_base + wm + i * 16 + quad * 4;
            #pragma unroll
            for (int rg = 0; rg < 4; ++rg)
                ob[(size_t)(o + rg) * 3136] = acc[i][j][rg] * al[i][rg];
        }
    }
}

// ---------------------------------------------------------------------------
extern "C" void kernel_launch(void* const* d_in, const int* in_sizes, int n_in,
                              void* d_out, int out_size, void* d_ws, size_t ws_size,
                              hipStream_t stream) {
    const float* x = (const float*)d_in[0];
    const float* w = (const float*)d_in[1];
    float* out = (float*)d_out;

    char* ws = (char*)d_ws;
    // xp: 32*32*58*58*8 bf16 = 55,115,776 B
    u16*   xp    = (u16*)ws;
    u16*   wq    = (u16*)(ws + 55115776);           // 256*2304 bf16 = 1,179,648 B
    float* alpha = (float*)(ws + 55115776 + 1179648);

    quant_kernel<<<256, 256, 0, stream>>>(w, wq, alpha);
    hipMemsetAsync(xp, 0, 55115776, stream);        // zero borders (bf16 0 = 0x0000)
    dim3 pg(32, 32, 4);
    pad_kernel<<<pg, 256, 0, stream>>>(x, xp);
    conv_gemm<<<784 * 2, 256, 0, stream>>>(wq, xp, alpha, out);
}